// Round 3
// baseline (705.496 us; speedup 1.0000x reference)
//
#include <hip/hip_runtime.h>
#include <math.h>

typedef unsigned int uint32;
typedef unsigned long long uint64;

#define NN      16384   // row length
#define THREADS 256
#define VPT     16      // float4 loads per thread (64 elements/thread)
#define NCOPY   16      // histogram copies to reduce LDS atomic contention
#define HSTRIDE 17      // padded stride: conflict-free copy-combine reads
#define EQ_CAP  256     // capacity for ==threshold index list

// Near-correctly-rounded float log, computed in double (~25 fp64 ops vs ~100
// for library log(double)). Two paths:
//  - |x-1| < 2^-6: log1p Taylor deg-10 on exact f=x-1 (handles cancellation;
//    this is where the top-k-critical u~1 elements live).
//  - else: 128-entry table: log(x) = e*ln2 - log(rcp_c) + log1p(m*rcp_c - 1),
//    |r| <= 2^-8, deg-6 poly. Abs err ~1e-15 << half-ulp budget (>=2e-10).
__device__ __forceinline__ float cr_logf(float x, const double2* __restrict__ tab)
{
    const float d = x - 1.0f;
    if (fabsf(d) < 0.015625f) {
        const double f = (double)d;            // exact
        double q;
        q = -1.0/10.0;
        q = fma(q, f,  1.0/9.0);
        q = fma(q, f, -1.0/8.0);
        q = fma(q, f,  1.0/7.0);
        q = fma(q, f, -1.0/6.0);
        q = fma(q, f,  1.0/5.0);
        q = fma(q, f, -1.0/4.0);
        q = fma(q, f,  1.0/3.0);
        q = fma(q, f, -1.0/2.0);
        return (float)fma(f*f, q, f);
    }
    const uint32 xb = __float_as_uint(x);
    const int    e  = (int)(xb >> 23) - 127;
    const uint32 mb = xb & 0x7FFFFFu;
    const float  mf = __uint_as_float(mb | 0x3F800000u);   // m in [1,2)
    const double2 t = tab[mb >> 16];                       // {rcp_c, -log(rcp_c)}
    const double r  = fma((double)mf, t.x, -1.0);          // |r| <= 2^-8
    double q;
    q = -1.0/6.0;
    q = fma(q, r,  1.0/5.0);
    q = fma(q, r, -1.0/4.0);
    q = fma(q, r,  1.0/3.0);
    q = fma(q, r, -1.0/2.0);
    const double lm = fma(r*r, q, r) + t.y;
    return (float)fma((double)e, 0x1.62e42fefa39efp-1, lm);
}

__global__ __launch_bounds__(THREADS)
void imle_topk_kernel(const float* __restrict__ logits,
                      const float* __restrict__ noise,
                      const int*   __restrict__ kptr,
                      float*       __restrict__ out,
                      int Brows)
{
    __shared__ double2 tab[128];
    __shared__ int     hist[256 * HSTRIDE];
    __shared__ int     finalh[256];
    __shared__ uint32  sh_pref;
    __shared__ int     sh_rem;
    __shared__ int     eq_cnt;
    __shared__ int     eq_idx[EQ_CAP];

    const int row  = blockIdx.x;          // 0 .. S*B-1
    const int lrow = row % Brows;         // logits row
    const int tid  = threadIdx.x;
    const int k    = kptr[0];
    const int lane = tid & 63;
    const int wid  = tid >> 6;

    if (tid < 128) {
        const double mc  = 1.0 + ((double)(2 * tid + 1)) * (1.0 / 256.0);
        const double rcp = 1.0 / mc;
        tab[tid] = make_double2(rcp, -log(rcp));
    }
    if (tid == 0) eq_cnt = 0;
    __syncthreads();

    const float4* __restrict__ np4 = (const float4*)(noise  + (size_t)row  * NN);
    const float4* __restrict__ lp4 = (const float4*)(logits + (size_t)lrow * NN);
    float4*       __restrict__ op4 = (float4*)(out + (size_t)row * NN);

    // ---- 1. load + perturb -> sortable uint keys. FULL unroll: key[j][c]
    // must be compile-time-indexed so the array stays in VGPRs (a partial
    // unroll here sent it to scratch: VGPR 84->36, FETCH_SIZE x4). ----
    uint32 key[VPT][4];

    #pragma unroll
    for (int j = 0; j < VPT; ++j) {
        const int v = tid + j * THREADS;
        const float4 u4 = np4[v];
        const float4 l4 = lp4[v];
        const float uu[4] = {u4.x, u4.y, u4.z, u4.w};
        const float ll[4] = {l4.x, l4.y, l4.z, l4.w};
        #pragma unroll
        for (int c = 0; c < 4; ++c) {
            const float t1 = cr_logf(uu[c], tab);   // log(u)       (fp32 round)
            const float t2 = cr_logf(-t1,  tab);    // log(-log(u)) (fp32 round)
            const float p  = ll[c] - t2;            // logits + gumbel
            const uint32 b = __float_as_uint(p);
            key[j][c] = (b & 0x80000000u) ? ~b : (b | 0x80000000u);
        }
    }

    // ---- 2. exact k-th largest via 4x8-bit radix select ----
    uint32 prefix = 0, himask = 0;
    int    rem    = k;
    const int copy = tid & (NCOPY - 1);

    #pragma unroll
    for (int dgt = 3; dgt >= 0; --dgt) {
        const int sh = 8 * dgt;

        #pragma unroll
        for (int i = 0; i < (256 * HSTRIDE + THREADS - 1) / THREADS; ++i) {
            const int a = tid + i * THREADS;
            if (a < 256 * HSTRIDE) hist[a] = 0;
        }
        __syncthreads();

        #pragma unroll
        for (int j = 0; j < VPT; ++j) {
            #pragma unroll
            for (int c = 0; c < 4; ++c) {
                const uint32 kk = key[j][c];
                if ((kk & himask) == prefix)
                    atomicAdd(&hist[(((kk >> sh) & 255u) * HSTRIDE) + copy], 1);
            }
        }
        __syncthreads();

        {   // combine copies: one bin per thread (stride 17 -> conflict-free)
            int ssum = 0;
            #pragma unroll
            for (int q = 0; q < NCOPY; ++q) ssum += hist[tid * HSTRIDE + q];
            finalh[tid] = ssum;
        }
        __syncthreads();

        // wave-parallel suffix scan (wave 0): find highest bin b with
        // suffix_count(b) >= rem
        if (wid == 0) {
            const int lo = 252 - 4 * lane;       // lane 0 covers top bins
            const int s  = finalh[lo] + finalh[lo+1] + finalh[lo+2] + finalh[lo+3];
            int p = s;
            #pragma unroll
            for (int off = 1; off < 64; off <<= 1) {
                const int v = __shfl_up(p, off);
                if (lane >= off) p += v;
            }
            const uint64 bal = __ballot(p >= rem);
            const int l0 = __ffsll((long long)bal) - 1;
            if (lane == l0) {
                int acc = p - s;                 // exclusive (bins above group)
                int b   = lo + 3;
                for (;;) {
                    const int h = finalh[b];
                    if (acc + h >= rem || b == lo) break;
                    acc += h; --b;
                }
                sh_pref = prefix | ((uint32)b << sh);
                sh_rem  = rem - acc;
            }
        }
        __syncthreads();
        prefix = sh_pref;
        rem    = sh_rem;
        himask |= (0xFFu << sh);
    }

    const uint32 T     = prefix;   // exact key of the k-th largest
    const int    tneed = rem;      // how many ==T to select (lowest indices)

    // ---- 3. write mask; collect ==T indices ----
    #pragma unroll
    for (int j = 0; j < VPT; ++j) {
        const int v = tid + j * THREADS;
        float o[4];
        #pragma unroll
        for (int c = 0; c < 4; ++c) {
            const uint32 kk = key[j][c];
            o[c] = (kk > T) ? 1.0f : 0.0f;
            if (kk == T) {
                const int slot = atomicAdd(&eq_cnt, 1);
                if (slot < EQ_CAP) eq_idx[slot] = 4 * v + c;
            }
        }
        op4[v] = make_float4(o[0], o[1], o[2], o[3]);
    }
    __syncthreads();

    // ---- 4. tie-break: lowest tneed indices among ==T get 1.0 ----
    if (tid == 0) {
        int e = eq_cnt; if (e > EQ_CAP) e = EQ_CAP;
        float* orow = out + (size_t)row * NN;
        for (int it = 0; it < tneed; ++it) {
            int mn = 0x7FFFFFFF, mpos = -1;
            for (int q = 0; q < e; ++q) {
                const int idx = eq_idx[q];
                if (idx >= 0 && idx < mn) { mn = idx; mpos = q; }
            }
            if (mpos < 0) break;
            eq_idx[mpos] = -1;
            orow[mn] = 1.0f;
        }
    }
}

extern "C" void kernel_launch(void* const* d_in, const int* in_sizes, int n_in,
                              void* d_out, int out_size, void* d_ws, size_t ws_size,
                              hipStream_t stream) {
    const float* logits = (const float*)d_in[0];
    const float* noise  = (const float*)d_in[1];
    const int*   kptr   = (const int*)d_in[2];
    float*       out    = (float*)d_out;

    const int rows  = in_sizes[1] / NN;   // S*B = 2048
    const int Brows = in_sizes[0] / NN;   // B   = 128

    imle_topk_kernel<<<rows, THREADS, 0, stream>>>(logits, noise, kptr, out, Brows);
}

// Round 4
// 279.054 us; speedup vs baseline: 2.5282x; 2.5282x over previous
//
#include <hip/hip_runtime.h>
#include <math.h>

typedef unsigned int uint32;
typedef unsigned long long uint64;

#define NN      16384   // row length
#define THREADS 256
#define VPT     16      // float4 loads per thread (64 elements/thread)
#define NCOPY   16      // histogram copies to reduce LDS atomic contention
#define EQ_CAP  256     // capacity for ==threshold index list

// Branch-free, LDS-free near-correctly-rounded float log via double atanh:
//   fold m in [1,2) -> [0.75,1.5)  (exact exponent step, kills e*ln2 cancel)
//   s = (m-1)/(m+1)  (num/den exact in double; rcp_f32 seed + 2 Newton)
//   log(m) = 2s + 2s*s2*(1/3 + s2/5 + ... + s2^10/23),  s2 <= 0.04
//   result = e*ln2_hi + (e*ln2_lo + log(m))   (fdlibm split, e*ln2_hi exact)
// abs err ~3e-16 relative -> far inside the float half-ulp budget everywhere.
__device__ __forceinline__ float cr_logf(float x)
{
    const uint32 xb = __float_as_uint(x);
    const uint32 ge = (xb >> 22) & 1u;                    // m >= 1.5 ?
    const int    e  = (int)(xb >> 23) - 127 + (int)ge;
    const uint32 mb = (xb & 0x7FFFFFu) | 0x3F800000u;     // m in [1,2)
    const float  mh = __uint_as_float(mb - (ge << 23));   // fold -> [0.75,1.5)
    const double md  = (double)mh;
    const double num = md - 1.0;                          // exact
    const double den = md + 1.0;                          // exact
    double r = (double)__builtin_amdgcn_rcpf((float)den); // seed ~1e-7
    r = r * fma(-den, r, 2.0);                            // ~1e-14
    r = r * fma(-den, r, 2.0);                            // ~2e-16
    const double s  = num * r;                            // |s| <= 0.2
    const double s2 = s * s;                              // <= 0.04
    double q;
    q = 1.0/23.0;
    q = fma(q, s2, 1.0/21.0);
    q = fma(q, s2, 1.0/19.0);
    q = fma(q, s2, 1.0/17.0);
    q = fma(q, s2, 1.0/15.0);
    q = fma(q, s2, 1.0/13.0);
    q = fma(q, s2, 1.0/11.0);
    q = fma(q, s2, 1.0/9.0);
    q = fma(q, s2, 1.0/7.0);
    q = fma(q, s2, 1.0/5.0);
    q = fma(q, s2, 1.0/3.0);
    const double s3 = s2 * (2.0 * s);
    const double lm = fma(s3, q, 2.0 * s);
    const double ed = (double)e;
    const double LN2_HI = 6.93147180369123816490e-01;     // fdlibm ln2_hi
    const double LN2_LO = 1.90821492927058770002e-10;     // fdlibm ln2_lo
    return (float)fma(ed, LN2_HI, fma(ed, LN2_LO, lm));
}

__global__ __launch_bounds__(THREADS, 4)
void imle_topk_kernel(const float* __restrict__ logits,
                      const float* __restrict__ noise,
                      const int*   __restrict__ kptr,
                      float*       __restrict__ out,
                      int Brows)
{
    __shared__ int     hist[256 * NCOPY];
    __shared__ int     finalh[256];
    __shared__ uint32  sh_pref;
    __shared__ int     sh_rem;
    __shared__ int     eq_cnt;
    __shared__ int     eq_idx[EQ_CAP];

    const int row  = blockIdx.x;          // 0 .. S*B-1
    const int lrow = row % Brows;         // logits row
    const int tid  = threadIdx.x;
    const int k    = kptr[0];
    const int lane = tid & 63;
    const int wid  = tid >> 6;

    if (tid == 0) eq_cnt = 0;

    const float4* __restrict__ np4 = (const float4*)(noise  + (size_t)row  * NN);
    const float4* __restrict__ lp4 = (const float4*)(logits + (size_t)lrow * NN);
    float4*       __restrict__ op4 = (float4*)(out + (size_t)row * NN);

    // ---- 1. load + perturb -> sortable uint keys. FULL unroll: key[j][c]
    // must be compile-time-indexed (partial unroll -> scratch, round 2). ----
    uint32 key[VPT][4];

    #pragma unroll
    for (int j = 0; j < VPT; ++j) {
        const int v = tid + j * THREADS;
        const float4 u4 = np4[v];
        const float4 l4 = lp4[v];
        const float uu[4] = {u4.x, u4.y, u4.z, u4.w};
        const float ll[4] = {l4.x, l4.y, l4.z, l4.w};
        #pragma unroll
        for (int c = 0; c < 4; ++c) {
            const float t1 = cr_logf(uu[c]);   // log(u)       (fp32 round)
            const float t2 = cr_logf(-t1);     // log(-log(u)) (fp32 round)
            const float p  = ll[c] - t2;       // logits + gumbel
            const uint32 b = __float_as_uint(p);
            key[j][c] = (b & 0x80000000u) ? ~b : (b | 0x80000000u);
        }
    }

    __syncthreads();   // eq_cnt init visible

    // ---- 2. exact k-th largest via 4x8-bit radix select ----
    uint32 prefix = 0, himask = 0;
    int    rem    = k;
    const int copy = tid & (NCOPY - 1);

    #pragma unroll
    for (int dgt = 3; dgt >= 0; --dgt) {
        const int sh = 8 * dgt;

        #pragma unroll
        for (int i = 0; i < (256 * NCOPY) / THREADS; ++i)
            hist[tid + i * THREADS] = 0;
        __syncthreads();

        #pragma unroll
        for (int j = 0; j < VPT; ++j) {
            #pragma unroll
            for (int c = 0; c < 4; ++c) {
                const uint32 kk = key[j][c];
                if ((kk & himask) == prefix)
                    atomicAdd(&hist[(((kk >> sh) & 255u) * NCOPY) + copy], 1);
            }
        }
        __syncthreads();

        {   // combine copies: rotated read avoids the 32-way bank conflict
            int ssum = 0;
            #pragma unroll
            for (int q = 0; q < NCOPY; ++q)
                ssum += hist[tid * NCOPY + ((q + tid) & (NCOPY - 1))];
            finalh[tid] = ssum;
        }
        __syncthreads();

        // wave-parallel suffix scan (wave 0): find highest bin b with
        // suffix_count(b) >= rem
        if (wid == 0) {
            const int lo = 252 - 4 * lane;       // lane 0 covers top bins
            const int s  = finalh[lo] + finalh[lo+1] + finalh[lo+2] + finalh[lo+3];
            int p = s;
            #pragma unroll
            for (int off = 1; off < 64; off <<= 1) {
                const int v = __shfl_up(p, off);
                if (lane >= off) p += v;
            }
            const uint64 bal = __ballot(p >= rem);
            const int l0 = __ffsll((long long)bal) - 1;
            if (lane == l0) {
                int acc = p - s;                 // exclusive (bins above group)
                int b   = lo + 3;
                for (;;) {
                    const int h = finalh[b];
                    if (acc + h >= rem || b == lo) break;
                    acc += h; --b;
                }
                sh_pref = prefix | ((uint32)b << sh);
                sh_rem  = rem - acc;
            }
        }
        __syncthreads();
        prefix = sh_pref;
        rem    = sh_rem;
        himask |= (0xFFu << sh);
    }

    const uint32 T     = prefix;   // exact key of the k-th largest
    const int    tneed = rem;      // how many ==T to select (lowest indices)

    // ---- 3. write mask; collect ==T indices ----
    #pragma unroll
    for (int j = 0; j < VPT; ++j) {
        const int v = tid + j * THREADS;
        float o[4];
        #pragma unroll
        for (int c = 0; c < 4; ++c) {
            const uint32 kk = key[j][c];
            o[c] = (kk > T) ? 1.0f : 0.0f;
            if (kk == T) {
                const int slot = atomicAdd(&eq_cnt, 1);
                if (slot < EQ_CAP) eq_idx[slot] = 4 * v + c;
            }
        }
        op4[v] = make_float4(o[0], o[1], o[2], o[3]);
    }
    __syncthreads();

    // ---- 4. tie-break: lowest tneed indices among ==T get 1.0 ----
    if (tid == 0) {
        int e = eq_cnt; if (e > EQ_CAP) e = EQ_CAP;
        float* orow = out + (size_t)row * NN;
        for (int it = 0; it < tneed; ++it) {
            int mn = 0x7FFFFFFF, mpos = -1;
            for (int q = 0; q < e; ++q) {
                const int idx = eq_idx[q];
                if (idx >= 0 && idx < mn) { mn = idx; mpos = q; }
            }
            if (mpos < 0) break;
            eq_idx[mpos] = -1;
            orow[mn] = 1.0f;
        }
    }
}

extern "C" void kernel_launch(void* const* d_in, const int* in_sizes, int n_in,
                              void* d_out, int out_size, void* d_ws, size_t ws_size,
                              hipStream_t stream) {
    const float* logits = (const float*)d_in[0];
    const float* noise  = (const float*)d_in[1];
    const int*   kptr   = (const int*)d_in[2];
    float*       out    = (float*)d_out;

    const int rows  = in_sizes[1] / NN;   // S*B = 2048
    const int Brows = in_sizes[0] / NN;   // B   = 128

    imle_topk_kernel<<<rows, THREADS, 0, stream>>>(logits, noise, kptr, out, Brows);
}

// Round 7
// 259.304 us; speedup vs baseline: 2.7207x; 1.0762x over previous
//
#include <hip/hip_runtime.h>
#include <math.h>

typedef unsigned int uint32;
typedef unsigned long long uint64;

#define NN       16384   // row length
#define THREADS  256
#define VPT      16      // float4 loads per thread (64 elements/thread)
#define NCOPY    16      // histogram copies to reduce LDS atomic contention
#define CAND_CAP 1024    // candidate list capacity (expected ~35)

// ---- order-preserving float <-> uint key ----
__device__ __forceinline__ uint32 fkey(float p) {
    const uint32 b = __float_as_uint(p);
    return (b & 0x80000000u) ? ~b : (b | 0x80000000u);
}
__device__ __forceinline__ float fkey_dec(uint32 kk) {
    const uint32 b = (kk & 0x80000000u) ? (kk ^ 0x80000000u) : ~kk;
    return __uint_as_float(b);
}

// Branch-free, LDS-free near-correctly-rounded float log via double atanh
// (validated round 4: absmax 0.0). Used ONLY for ~35 candidates per row.
__device__ __forceinline__ float cr_logf(float x)
{
    const uint32 xb = __float_as_uint(x);
    const uint32 ge = (xb >> 22) & 1u;                    // m >= 1.5 ?
    const int    e  = (int)(xb >> 23) - 127 + (int)ge;
    const uint32 mb = (xb & 0x7FFFFFu) | 0x3F800000u;     // m in [1,2)
    const float  mh = __uint_as_float(mb - (ge << 23));   // fold -> [0.75,1.5)
    const double md  = (double)mh;
    const double num = md - 1.0;                          // exact
    const double den = md + 1.0;                          // exact
    double r = (double)__builtin_amdgcn_rcpf((float)den);
    r = r * fma(-den, r, 2.0);
    r = r * fma(-den, r, 2.0);
    const double s  = num * r;
    const double s2 = s * s;
    double q;
    q = 1.0/23.0;
    q = fma(q, s2, 1.0/21.0);
    q = fma(q, s2, 1.0/19.0);
    q = fma(q, s2, 1.0/17.0);
    q = fma(q, s2, 1.0/15.0);
    q = fma(q, s2, 1.0/13.0);
    q = fma(q, s2, 1.0/11.0);
    q = fma(q, s2, 1.0/9.0);
    q = fma(q, s2, 1.0/7.0);
    q = fma(q, s2, 1.0/5.0);
    q = fma(q, s2, 1.0/3.0);
    const double s3 = s2 * (2.0 * s);
    const double lm = fma(s3, q, 2.0 * s);
    const double ed = (double)e;
    const double LN2_HI = 6.93147180369123816490e-01;
    const double LN2_LO = 1.90821492927058770002e-10;
    return (float)fma(ed, LN2_HI, fma(ed, LN2_LO, lm));
}

// wave-0 suffix scan over finalh[256]: highest bin b with suffix>=rem.
__device__ __forceinline__ void select_byte(const int* __restrict__ finalh,
                                            int rem_in, uint32* sh_bin,
                                            int* sh_rem, int lane, int wid)
{
    if (wid == 0) {
        const int lo = 252 - 4 * lane;       // lane 0 covers top bins
        const int s  = finalh[lo] + finalh[lo+1] + finalh[lo+2] + finalh[lo+3];
        int p = s;
        #pragma unroll
        for (int off = 1; off < 64; off <<= 1) {
            const int v = __shfl_up(p, off);
            if (lane >= off) p += v;
        }
        const uint64 bal = __ballot(p >= rem_in);
        const int l0 = __ffsll((long long)bal) - 1;
        if (lane == l0) {
            int acc = p - s;                 // exclusive (bins above group)
            int b   = lo + 3;
            for (;;) {
                const int h = finalh[b];
                if (acc + h >= rem_in || b == lo) break;
                acc += h; --b;
            }
            *sh_bin = (uint32)b;
            *sh_rem = rem_in - acc;
        }
    }
}

__global__ __launch_bounds__(THREADS, 4)
void imle_topk_kernel(const float* __restrict__ logits,
                      const float* __restrict__ noise,
                      const int*   __restrict__ kptr,
                      float*       __restrict__ out,
                      int Brows)
{
    __shared__ int    hist[256 * NCOPY];
    __shared__ int    finalh[256];
    __shared__ uint32 sh_bin;
    __shared__ int    sh_rem;
    __shared__ int    cand_cnt;
    __shared__ int    cand_idx[CAND_CAP];
    __shared__ uint32 cand_key[CAND_CAP];

    const int row  = blockIdx.x;          // 0 .. S*B-1
    const int lrow = row % Brows;         // logits row
    const int tid  = threadIdx.x;
    const int k    = kptr[0];
    const int lane = tid & 63;
    const int wid  = tid >> 6;

    if (tid == 0) cand_cnt = 0;

    const float4* __restrict__ np4 = (const float4*)(noise  + (size_t)row  * NN);
    const float4* __restrict__ lp4 = (const float4*)(logits + (size_t)lrow * NN);
    float4*       __restrict__ op4 = (float4*)(out + (size_t)row * NN);

    // ---- 1. approx keys (fp32, HW log) + coalesced zero-store of output.
    // abs err <= ~5e-6: HW v_log_f32 on the outer log is fine everywhere;
    // inner log(u) uses a 4-term log1p series for |u-1|<2^-6 (the HW log's
    // absolute error floor near 1 would wreck exactly the top-k elements).
    // FULL unroll: key[][] must be compile-time-indexed (round-2 lesson). ----
    uint32 key[VPT][4];
    const float4 zero4 = make_float4(0.f, 0.f, 0.f, 0.f);

    #pragma unroll
    for (int j = 0; j < VPT; ++j) {
        const int v = tid + j * THREADS;
        const float4 u4 = np4[v];
        const float4 l4 = lp4[v];
        const float uu[4] = {u4.x, u4.y, u4.z, u4.w};
        const float ll[4] = {l4.x, l4.y, l4.z, l4.w};
        #pragma unroll
        for (int c = 0; c < 4; ++c) {
            const float u  = uu[c];
            const float d  = u - 1.0f;                          // exact
            const float t1g = __log2f(u) * 0.69314718056f;
            const float t1w = d * fmaf(d, fmaf(d, fmaf(d, -0.25f, 0.33333334f), -0.5f), 1.0f);
            const float t1 = (fabsf(d) < 0.015625f) ? t1w : t1g;  // log(u)
            const float t2 = __log2f(-t1) * 0.69314718056f;       // log(-log u)
            const float p  = ll[c] - t2;
            key[j][c] = fkey(p);
        }
        op4[v] = zero4;    // default output; winners overwrite after barriers
    }
    __syncthreads();       // covers cand_cnt init; zero-stores drained by sync

    // ---- 2a. radix pass on top byte (all elements) ----
    const int copy = tid & (NCOPY - 1);
    #pragma unroll
    for (int i = 0; i < (256 * NCOPY) / THREADS; ++i)
        hist[tid + i * THREADS] = 0;
    __syncthreads();
    #pragma unroll
    for (int j = 0; j < VPT; ++j) {
        #pragma unroll
        for (int c = 0; c < 4; ++c)
            atomicAdd(&hist[((key[j][c] >> 24) * NCOPY) + copy], 1);
    }
    __syncthreads();
    {
        int ssum = 0;
        #pragma unroll
        for (int q = 0; q < NCOPY; ++q)
            ssum += hist[tid * NCOPY + ((q + tid) & (NCOPY - 1))];
        finalh[tid] = ssum;
    }
    __syncthreads();
    select_byte(finalh, k, &sh_bin, &sh_rem, lane, wid);
    __syncthreads();
    const uint32 b3  = sh_bin;
    const int    rem = sh_rem;

    // ---- 2b. radix pass on bits 16..23 (elements with top byte == b3) ----
    __syncthreads();   // protect hist re-zero vs. stragglers reading it
    #pragma unroll
    for (int i = 0; i < (256 * NCOPY) / THREADS; ++i)
        hist[tid + i * THREADS] = 0;
    __syncthreads();
    #pragma unroll
    for (int j = 0; j < VPT; ++j) {
        #pragma unroll
        for (int c = 0; c < 4; ++c) {
            const uint32 kk = key[j][c];
            if ((kk >> 24) == b3)
                atomicAdd(&hist[(((kk >> 16) & 255u) * NCOPY) + copy], 1);
        }
    }
    __syncthreads();
    {
        int ssum = 0;
        #pragma unroll
        for (int q = 0; q < NCOPY; ++q)
            ssum += hist[tid * NCOPY + ((q + tid) & (NCOPY - 1))];
        finalh[tid] = ssum;
    }
    __syncthreads();
    select_byte(finalh, rem, &sh_bin, &sh_rem, lane, wid);
    __syncthreads();
    const uint32 b2 = sh_bin;

    // ---- 3. candidate band: approx key >= encode(binLower - margin).
    // margin 3e-4 >> 2*(approx abs err ~5e-6)  =>  exact top-k subset of C. ----
    const uint32 Lkey  = (b3 << 24) | (b2 << 16);
    const float  Lf    = fkey_dec(Lkey);
    const float  TloF  = Lf - (3e-4f + fabsf(Lf) * 2e-6f);
    const uint32 Tlo   = fkey(TloF);

    #pragma unroll
    for (int j = 0; j < VPT; ++j) {
        const int v = tid + j * THREADS;
        #pragma unroll
        for (int c = 0; c < 4; ++c) {
            if (key[j][c] >= Tlo) {
                const int slot = atomicAdd(&cand_cnt, 1);
                if (slot < CAND_CAP) cand_idx[slot] = 4 * v + c;
            }
        }
    }
    __syncthreads();
    int n = cand_cnt; if (n > CAND_CAP) n = CAND_CAP;

    // ---- 4. exact fp64 recompute, candidates only (~35/row) ----
    const float* __restrict__ nrow = noise  + (size_t)row  * NN;
    const float* __restrict__ lrp  = logits + (size_t)lrow * NN;
    for (int t = tid; t < n; t += THREADS) {
        const int   idx = cand_idx[t];
        const float t1  = cr_logf(nrow[idx]);
        const float t2  = cr_logf(-t1);
        cand_key[t] = fkey(lrp[idx] - t2);
    }
    __syncthreads();

    // ---- 5. exact rank with lowest-index tie-break; winners write 1.0 ----
    float* __restrict__ orow = out + (size_t)row * NN;
    for (int t = tid; t < n; t += THREADS) {
        const uint32 mk = cand_key[t];
        const int    mi = cand_idx[t];
        int rank = 0;
        for (int j2 = 0; j2 < n; ++j2) {
            const uint32 ok = cand_key[j2];
            rank += (ok > mk || (ok == mk && cand_idx[j2] < mi)) ? 1 : 0;
        }
        if (rank < k) orow[mi] = 1.0f;
    }
}

extern "C" void kernel_launch(void* const* d_in, const int* in_sizes, int n_in,
                              void* d_out, int out_size, void* d_ws, size_t ws_size,
                              hipStream_t stream) {
    const float* logits = (const float*)d_in[0];
    const float* noise  = (const float*)d_in[1];
    const int*   kptr   = (const int*)d_in[2];
    float*       out    = (float*)d_out;

    const int rows  = in_sizes[1] / NN;   // S*B = 2048
    const int Brows = in_sizes[0] / NN;   // B   = 128

    imle_topk_kernel<<<rows, THREADS, 0, stream>>>(logits, noise, kptr, out, Brows);
}

// Round 8
// 252.020 us; speedup vs baseline: 2.7994x; 1.0289x over previous
//
#include <hip/hip_runtime.h>
#include <math.h>

typedef unsigned int uint32;
typedef unsigned long long uint64;

#define NN       16384   // row length
#define THREADS  512
#define VPT      8       // float4 loads per thread (32 elements/thread)
#define NCOPY    8       // histogram copies (LDS atomic contention relief)
#define CAND_CAP 768     // candidate list capacity (expected ~35-150)

// ---- order-preserving float <-> uint key ----
__device__ __forceinline__ uint32 fkey(float p) {
    const uint32 b = __float_as_uint(p);
    return (b & 0x80000000u) ? ~b : (b | 0x80000000u);
}

// Branch-free, LDS-free near-correctly-rounded float log via double atanh
// (validated rounds 4/7: absmax 0.0). Used ONLY for candidates (~100/row).
__device__ __forceinline__ float cr_logf(float x)
{
    const uint32 xb = __float_as_uint(x);
    const uint32 ge = (xb >> 22) & 1u;                    // m >= 1.5 ?
    const int    e  = (int)(xb >> 23) - 127 + (int)ge;
    const uint32 mb = (xb & 0x7FFFFFu) | 0x3F800000u;     // m in [1,2)
    const float  mh = __uint_as_float(mb - (ge << 23));   // fold -> [0.75,1.5)
    const double md  = (double)mh;
    const double num = md - 1.0;                          // exact
    const double den = md + 1.0;                          // exact
    double r = (double)__builtin_amdgcn_rcpf((float)den);
    r = r * fma(-den, r, 2.0);
    r = r * fma(-den, r, 2.0);
    const double s  = num * r;
    const double s2 = s * s;
    double q;
    q = 1.0/23.0;
    q = fma(q, s2, 1.0/21.0);
    q = fma(q, s2, 1.0/19.0);
    q = fma(q, s2, 1.0/17.0);
    q = fma(q, s2, 1.0/15.0);
    q = fma(q, s2, 1.0/13.0);
    q = fma(q, s2, 1.0/11.0);
    q = fma(q, s2, 1.0/9.0);
    q = fma(q, s2, 1.0/7.0);
    q = fma(q, s2, 1.0/5.0);
    q = fma(q, s2, 1.0/3.0);
    const double s3 = s2 * (2.0 * s);
    const double lm = fma(s3, q, 2.0 * s);
    const double ed = (double)e;
    const double LN2_HI = 6.93147180369123816490e-01;
    const double LN2_LO = 1.90821492927058770002e-10;
    return (float)fma(ed, LN2_HI, fma(ed, LN2_LO, lm));
}

// wave-0 suffix scan over finalh[256]: highest bin b with suffix>=rem.
__device__ __forceinline__ void select_byte(const int* __restrict__ finalh,
                                            int rem_in, uint32* sh_bin,
                                            int* sh_rem, int lane, int wid)
{
    if (wid == 0) {
        const int lo = 252 - 4 * lane;       // lane 0 covers top bins
        const int s  = finalh[lo] + finalh[lo+1] + finalh[lo+2] + finalh[lo+3];
        int p = s;
        #pragma unroll
        for (int off = 1; off < 64; off <<= 1) {
            const int v = __shfl_up(p, off);
            if (lane >= off) p += v;
        }
        const uint64 bal = __ballot(p >= rem_in);
        const int l0 = __ffsll((long long)bal) - 1;
        if (lane == l0) {
            int acc = p - s;                 // exclusive (bins above group)
            int b   = lo + 3;
            for (;;) {
                const int h = finalh[b];
                if (acc + h >= rem_in || b == lo) break;
                acc += h; --b;
            }
            *sh_bin = (uint32)b;
            *sh_rem = rem_in - acc;
        }
    }
}

__global__ __launch_bounds__(THREADS, 8)
void imle_topk_kernel(const float* __restrict__ logits,
                      const float* __restrict__ noise,
                      const int*   __restrict__ kptr,
                      float*       __restrict__ out,
                      int Brows)
{
    __shared__ int    hist[256 * NCOPY];
    __shared__ int    finalh[256];
    __shared__ uint32 sh_bin;
    __shared__ int    sh_rem;
    __shared__ int    cand_cnt;
    __shared__ int    cand_idx[CAND_CAP];
    __shared__ uint32 cand_key[CAND_CAP];

    const int row  = blockIdx.x;          // 0 .. S*B-1
    const int lrow = row % Brows;         // logits row
    const int tid  = threadIdx.x;
    const int k    = kptr[0];
    const int lane = tid & 63;
    const int wid  = tid >> 6;

    if (tid == 0) cand_cnt = 0;

    const float4* __restrict__ np4 = (const float4*)(noise  + (size_t)row  * NN);
    const float4* __restrict__ lp4 = (const float4*)(logits + (size_t)lrow * NN);
    float4*       __restrict__ op4 = (float4*)(out + (size_t)row * NN);

    // ---- 1. approx keys (fp32, HW log), keep only TOP 16 BITS packed
    // 2-per-VGPR (16 VGPRs of key state -> 8 waves/EU occupancy).
    // abs err <= ~5e-6; inner log(u) patched with log1p series near u=1.
    // Zeros stored coalesced here; winners overwrite in phase 5. ----
    uint32 pk[VPT][2];
    const float4 zero4 = make_float4(0.f, 0.f, 0.f, 0.f);

    #pragma unroll
    for (int j = 0; j < VPT; ++j) {
        const int v = tid + j * THREADS;
        const float4 u4 = np4[v];
        const float4 l4 = lp4[v];
        const float uu[4] = {u4.x, u4.y, u4.z, u4.w};
        const float ll[4] = {l4.x, l4.y, l4.z, l4.w};
        uint32 k16[4];
        #pragma unroll
        for (int c = 0; c < 4; ++c) {
            const float u  = uu[c];
            const float d  = u - 1.0f;                          // exact
            const float t1g = __log2f(u) * 0.69314718056f;
            const float t1w = d * fmaf(d, fmaf(d, fmaf(d, -0.25f, 0.33333334f), -0.5f), 1.0f);
            const float t1 = (fabsf(d) < 0.015625f) ? t1w : t1g;  // log(u)
            const float t2 = __log2f(-t1) * 0.69314718056f;       // log(-log u)
            const float p  = ll[c] - t2;
            k16[c] = fkey(p) >> 16;
        }
        pk[j][0] = k16[0] | (k16[1] << 16);
        pk[j][1] = k16[2] | (k16[3] << 16);
        op4[v] = zero4;
    }
    __syncthreads();       // covers cand_cnt init

    // ---- 2a. radix pass on top byte (all elements) ----
    const int copy = tid & (NCOPY - 1);
    #pragma unroll
    for (int i = 0; i < (256 * NCOPY) / THREADS; ++i)
        hist[tid + i * THREADS] = 0;
    __syncthreads();
    #pragma unroll
    for (int j = 0; j < VPT; ++j) {
        const uint32 a = pk[j][0], b = pk[j][1];
        atomicAdd(&hist[((a >>  8) & 255u) * NCOPY + copy], 1);
        atomicAdd(&hist[((a >> 24)       ) * NCOPY + copy], 1);
        atomicAdd(&hist[((b >>  8) & 255u) * NCOPY + copy], 1);
        atomicAdd(&hist[((b >> 24)       ) * NCOPY + copy], 1);
    }
    __syncthreads();
    if (tid < 256) {
        int ssum = 0;
        #pragma unroll
        for (int q = 0; q < NCOPY; ++q)
            ssum += hist[tid * NCOPY + ((q + tid) & (NCOPY - 1))];
        finalh[tid] = ssum;
    }
    __syncthreads();
    select_byte(finalh, k, &sh_bin, &sh_rem, lane, wid);
    __syncthreads();
    const uint32 b3  = sh_bin;
    const int    rem = sh_rem;

    // ---- 2b. radix pass on low byte of k16 (elements with top byte == b3) ----
    __syncthreads();   // protect hist re-zero vs. stragglers reading it
    #pragma unroll
    for (int i = 0; i < (256 * NCOPY) / THREADS; ++i)
        hist[tid + i * THREADS] = 0;
    __syncthreads();
    #pragma unroll
    for (int j = 0; j < VPT; ++j) {
        #pragma unroll
        for (int h = 0; h < 2; ++h) {
            const uint32 w  = pk[j][h];
            const uint32 ka = w & 0xFFFFu;
            const uint32 kb = w >> 16;
            if ((ka >> 8) == b3) atomicAdd(&hist[(ka & 255u) * NCOPY + copy], 1);
            if ((kb >> 8) == b3) atomicAdd(&hist[(kb & 255u) * NCOPY + copy], 1);
        }
    }
    __syncthreads();
    if (tid < 256) {
        int ssum = 0;
        #pragma unroll
        for (int q = 0; q < NCOPY; ++q)
            ssum += hist[tid * NCOPY + ((q + tid) & (NCOPY - 1))];
        finalh[tid] = ssum;
    }
    __syncthreads();
    select_byte(finalh, rem, &sh_bin, &sh_rem, lane, wid);
    __syncthreads();
    const uint32 b2 = sh_bin;

    // ---- 3. candidate band at 16-bit granularity: k16 >= T16 - 2.
    // granule (>=4.9e-4 in value here) >> 2*approx err (~1e-5)  =>
    // provable superset of the exact top-k. ----
    const uint32 T16   = (b3 << 8) | b2;
    const uint32 Tlo16 = (T16 >= 2u) ? (T16 - 2u) : 0u;

    #pragma unroll
    for (int j = 0; j < VPT; ++j) {
        const int v = tid + j * THREADS;
        #pragma unroll
        for (int h = 0; h < 2; ++h) {
            const uint32 w  = pk[j][h];
            const uint32 ka = w & 0xFFFFu;
            const uint32 kb = w >> 16;
            if (ka >= Tlo16) {
                const int slot = atomicAdd(&cand_cnt, 1);
                if (slot < CAND_CAP) cand_idx[slot] = 4 * v + 2 * h;
            }
            if (kb >= Tlo16) {
                const int slot = atomicAdd(&cand_cnt, 1);
                if (slot < CAND_CAP) cand_idx[slot] = 4 * v + 2 * h + 1;
            }
        }
    }
    __syncthreads();
    int n = cand_cnt; if (n > CAND_CAP) n = CAND_CAP;

    // ---- 4. exact fp64 recompute, candidates only ----
    const float* __restrict__ nrow = noise  + (size_t)row  * NN;
    const float* __restrict__ lrp  = logits + (size_t)lrow * NN;
    for (int t = tid; t < n; t += THREADS) {
        const int   idx = cand_idx[t];
        const float t1  = cr_logf(nrow[idx]);
        const float t2  = cr_logf(-t1);
        cand_key[t] = fkey(lrp[idx] - t2);
    }
    __syncthreads();

    // ---- 5. exact rank with lowest-index tie-break; winners write 1.0 ----
    float* __restrict__ orow = out + (size_t)row * NN;
    for (int t = tid; t < n; t += THREADS) {
        const uint32 mk = cand_key[t];
        const int    mi = cand_idx[t];
        int rank = 0;
        for (int j2 = 0; j2 < n; ++j2) {
            const uint32 ok = cand_key[j2];
            rank += (ok > mk || (ok == mk && cand_idx[j2] < mi)) ? 1 : 0;
        }
        if (rank < k) orow[mi] = 1.0f;
    }
}

extern "C" void kernel_launch(void* const* d_in, const int* in_sizes, int n_in,
                              void* d_out, int out_size, void* d_ws, size_t ws_size,
                              hipStream_t stream) {
    const float* logits = (const float*)d_in[0];
    const float* noise  = (const float*)d_in[1];
    const int*   kptr   = (const int*)d_in[2];
    float*       out    = (float*)d_out;

    const int rows  = in_sizes[1] / NN;   // S*B = 2048
    const int Brows = in_sizes[0] / NN;   // B   = 128

    imle_topk_kernel<<<rows, THREADS, 0, stream>>>(logits, noise, kptr, out, Brows);
}